// Round 14
// baseline (470.022 us; speedup 1.0000x reference)
//
#include <hip/hip_runtime.h>
#include <hip/hip_bf16.h>
#include <math.h>

#define EMBED 4096
#define SLEN 2048
#define HEADS 16
#define HDIM 256
#define ROT 64

typedef __bf16 bf16;
typedef __attribute__((ext_vector_type(8))) __bf16 bf16x8;
typedef __attribute__((ext_vector_type(4))) float f32x4;

__device__ __forceinline__ void async_copy16(const void* g, void* l) {
  __builtin_amdgcn_global_load_lds((const __attribute__((address_space(1))) void*)g,
                                   (__attribute__((address_space(3))) void*)l,
                                   16, 0, 0);
}

// ---------------- cast fp32 -> bf16 ----------------
__global__ __launch_bounds__(256) void cast_kernel(const float* __restrict__ in,
                                                   bf16* __restrict__ out, int n4) {
  int i = blockIdx.x * 256 + threadIdx.x;
  if (i >= n4) return;
  float4 v = ((const float4*)in)[i];
  bf16 o[4] __attribute__((aligned(8)));
  o[0] = (bf16)v.x; o[1] = (bf16)v.y; o[2] = (bf16)v.z; o[3] = (bf16)v.w;
  ((ushort4*)out)[i] = *(const ushort4*)o;
}

// ---------------- transpose + cast: Wt[n][k] = W[k][n] ----------------
__global__ __launch_bounds__(256) void transpose_cast(const float* __restrict__ W,
                                                      bf16* __restrict__ Wt) {
  __shared__ bf16 tile[64][65];
  int k0 = blockIdx.y * 64, n0 = blockIdx.x * 64;
  int tr = threadIdx.x >> 4, tc = threadIdx.x & 15;
#pragma unroll
  for (int i = 0; i < 4; i++) {
    int row = tr + i * 16;
    float4 v = *(const float4*)(W + (size_t)(k0 + row) * EMBED + n0 + tc * 4);
    tile[row][tc * 4 + 0] = (bf16)v.x;
    tile[row][tc * 4 + 1] = (bf16)v.y;
    tile[row][tc * 4 + 2] = (bf16)v.z;
    tile[row][tc * 4 + 3] = (bf16)v.w;
  }
  __syncthreads();
#pragma unroll
  for (int i = 0; i < 4; i++) {
    int nl = tr + i * 16;
    bf16 o[4] __attribute__((aligned(8)));
#pragma unroll
    for (int j = 0; j < 4; j++) o[j] = tile[tc * 4 + j][nl];
    *(ushort4*)(Wt + (size_t)(n0 + nl) * EMBED + k0 + tc * 4) = *(const ushort4*)o;
  }
}

// ---------------- pipelined GEMM: C[M,N] = A[M,K] * Bt[N,K]^T (bf16 in) -------
// R14: BM=BN=128, BK=64; 256 threads = 4 waves (2M x 2N), 64x64 per wave
// (IDENTICAL wave-level fragment/MFMA code to the proven R9 kernel).
// 2-slot LDS double buffer (64 KB) -> 2 blocks/CU (grid 512 = 2/CU): the
// sibling block's waves cover this block's vmcnt(0) drain + barrier bubbles
// (cross-block TLP — the m97-structure mechanism; 1-block/CU lockstep was the
// R13 residual). stage(t+1) issued FIRST each tile (full compute phase to
// land), one vmcnt(0)+barrier per tile. XOR-swizzle (T2, conflicts=0).
// MODE 1: rotary out (Q,K); 2: V-transposed; 3: fp32.
template <int MODE>
__global__ __launch_bounds__(256, 2) void gemm_pipe(const bf16* __restrict__ A,
                                                    const bf16* __restrict__ Bt,
                                                    void* __restrict__ Cout,
                                                    int M, int N, int K) {
  constexpr int BM = 128, BN = 128, BK = 64;
  __shared__ __align__(16) bf16 As[2][BM * BK];  // 2 x 16 KB
  __shared__ __align__(16) bf16 Bs[2][BN * BK];  // 2 x 16 KB
  int t = threadIdx.x;
  int lane = t & 63, w = t >> 6;
  int c16 = lane & 15, g4 = lane >> 4;
  int wm = w >> 1, wn = w & 1;
  int m0 = blockIdx.y * BM, n0 = blockIdx.x * BN;
  int nt = K / BK;

  f32x4 acc[4][4] = {};

  auto stage = [&](int kt, int slot) {
    const bf16* Asrc = A + (size_t)m0 * K + kt * BK;
    const bf16* Bsrc = Bt + (size_t)n0 * K + kt * BK;
    bf16* Ad = As[slot];
    bf16* Bd = Bs[slot];
#pragma unroll
    for (int i = 0; i < 4; i++) {  // A: 1024 chunks / 256 threads
      int c = i * 256 + t;
      int row = c >> 3, col8 = c & 7;
      async_copy16(Asrc + (size_t)row * K + ((col8 ^ (row & 7)) * 8), Ad + c * 8);
    }
#pragma unroll
    for (int i = 0; i < 4; i++) {  // B: 1024 chunks / 256 threads
      int c = i * 256 + t;
      int row = c >> 3, col8 = c & 7;
      async_copy16(Bsrc + (size_t)row * K + ((col8 ^ (row & 7)) * 8), Bd + c * 8);
    }
  };

  // prologue: tile 0 resident
  stage(0, 0);
  asm volatile("s_waitcnt vmcnt(0)" ::: "memory");
  __builtin_amdgcn_s_barrier();

  for (int kt = 0; kt < nt; kt++) {
    int slot = kt & 1;
    // issue next tile's staging FIRST: it has the whole compute phase to land
    if (kt + 1 < nt) stage(kt + 1, slot ^ 1);
    const bf16* Ab = As[slot];
    const bf16* Bb = Bs[slot];

    bf16x8 af[2][4], bfr[2][4];
#pragma unroll
    for (int kk = 0; kk < 2; kk++) {
#pragma unroll
      for (int fm = 0; fm < 4; fm++) {
        int row = wm * 64 + fm * 16 + c16;
        af[kk][fm] = *(const bf16x8*)(Ab + row * BK + (((kk * 4 + g4) ^ (row & 7)) * 8));
      }
#pragma unroll
      for (int fn = 0; fn < 4; fn++) {
        int row = wn * 64 + fn * 16 + c16;
        bfr[kk][fn] = *(const bf16x8*)(Bb + row * BK + (((kk * 4 + g4) ^ (row & 7)) * 8));
      }
    }
    __builtin_amdgcn_s_setprio(1);
#pragma unroll
    for (int kk = 0; kk < 2; kk++)
#pragma unroll
      for (int fm = 0; fm < 4; fm++)
#pragma unroll
        for (int fn = 0; fn < 4; fn++)
          acc[fm][fn] = __builtin_amdgcn_mfma_f32_16x16x32_bf16(af[kk][fm], bfr[kk][fn],
                                                                acc[fm][fn], 0, 0, 0);
    __builtin_amdgcn_s_setprio(0);
    // tile kt+1 must be resident before any wave reads it next iteration; the
    // sibling block on this CU covers the drain. Slot hazard: slot^1 is only
    // overwritten after the NEXT barrier, by which time its reads are done.
    asm volatile("s_waitcnt vmcnt(0)" ::: "memory");
    __builtin_amdgcn_s_barrier();
  }

  // epilogue
#pragma unroll
  for (int fm = 0; fm < 4; fm++) {
#pragma unroll
    for (int fn = 0; fn < 4; fn++) {
      int col = n0 + wn * 64 + fn * 16 + c16;
#pragma unroll
      for (int r = 0; r < 4; r++) {
        int row = m0 + wm * 64 + fm * 16 + g4 * 4 + r;
        float v = acc[fm][fn][r];
        if (MODE == 1) {
          int d = col & (HDIM - 1);
          if (d < ROT) {  // wave-uniform: (n0%256==0) && wn==0
            float pv = __shfl_xor(v, 1);
            int jj = d >> 1;
            float invf = __expf(-0.28782313662425575f * (float)jj);
            float ang = (float)row * invf;
            float sa, ca;
            sincosf(ang, &sa, &ca);
            v = v * ca + pv * sa;  // reference has NO negation in rotate_every_two
          }
        }
        if (MODE == 3) {
          ((float*)Cout)[(size_t)row * N + col] = v;
        } else if (MODE == 2) {
          ((bf16*)Cout)[(size_t)col * M + row] = (bf16)v;
        } else {
          ((bf16*)Cout)[(size_t)row * N + col] = (bf16)v;
        }
      }
    }
  }
}

// ---------------- causal flash attention (R13-proven, ping-pong K/V) ----------
// 256 blocks. head=(b&7)*2+((b>>3)&1) (2 heads/XCD), pair=b>>4; passes qt=pair
// then 31-pair -> exactly 33 kt-iterations/block. K,V SINGLE-buffered ping-pong:
// QK(t) | barrier A | stage K(t+1) | softmax | PV(t) | barrier B | stage V(t+1).
// XOR-swizzled LDS, defer-max (T13), per-lane lrow partials (R11).
__global__ __launch_bounds__(256, 2) void attn_kernel(const bf16* __restrict__ Q,
                                                      const bf16* __restrict__ Kmat,
                                                      const bf16* __restrict__ Vt,
                                                      bf16* __restrict__ O) {
  __shared__ __align__(16) bf16 Ks[64 * 256];   // [kv_row][d], swizzled (32 KB)
  __shared__ __align__(16) bf16 Vs[64 * 256];   // [d][kv_row], swizzled (32 KB)
  __shared__ __align__(16) bf16 Pl[4][16 * 64]; // per-wave P, swizzled (8 KB)
  int t = threadIdx.x, lane = t & 63, w = t >> 6;
  int c16 = lane & 15, g4 = lane >> 4;
  int b = blockIdx.x;
  int h = (b & 7) * 2 + ((b >> 3) & 1);
  int pair = b >> 4;

  auto stageK = [&](int kt) {
#pragma unroll
    for (int j = 0; j < 8; j++) {
      int c = j * 256 + t;
      int row = c >> 5, col8 = c & 31;
      async_copy16(Kmat + (size_t)(kt * 64 + row) * EMBED + h * HDIM +
                       ((col8 ^ (row & 7)) * 8),
                   Ks + (size_t)c * 8);
    }
  };
  auto stageV = [&](int kt) {
#pragma unroll
    for (int j = 0; j < 8; j++) {
      int c = j * 256 + t;
      int row = c >> 3, col8 = c & 7;
      async_copy16(Vt + (size_t)(h * HDIM + row) * SLEN + kt * 64 +
                       ((col8 ^ (row & 7)) * 8),
                   Vs + (size_t)c * 8);
    }
  };

  for (int pass = 0; pass < 2; ++pass) {
    int qt = pass ? (31 - pair) : pair;
    int q0w = qt * 64 + w * 16;

    bf16x8 qf[8];
    {
      const bf16* qp = Q + (size_t)(q0w + c16) * EMBED + h * HDIM + g4 * 8;
#pragma unroll
      for (int kk = 0; kk < 8; kk++) qf[kk] = *(const bf16x8*)(qp + kk * 32);
    }
    f32x4 acco[16] = {};
    float mrow[4], lrow[4];  // mrow row-uniform; lrow PER-LANE partial
#pragma unroll
    for (int r = 0; r < 4; r++) { mrow[r] = -1e30f; lrow[r] = 0.f; }

    __syncthreads();  // prev pass fully done with Ks/Vs
    stageK(0);
    stageV(0);
    __syncthreads();  // drain: K(0), V(0) resident

    for (int kt = 0; kt <= qt; kt++) {
      // ---- QK(t) from Ks ----
      f32x4 accs[4] = {};
      __builtin_amdgcn_s_setprio(1);
#pragma unroll
      for (int kk = 0; kk < 8; kk++) {
#pragma unroll
        for (int fn = 0; fn < 4; fn++) {
          int r = fn * 16 + c16;
          bf16x8 kf = *(const bf16x8*)(Ks + r * 256 + ((kk * 4 + g4) ^ (c16 & 7)) * 8);
          accs[fn] = __builtin_amdgcn_mfma_f32_16x16x32_bf16(qf[kk], kf, accs[fn], 0, 0, 0);
        }
      }
      __builtin_amdgcn_s_setprio(0);
      // barrier A: all QK reads of Ks done (frees Ks); implicit vmcnt(0)
      // drained V(t)'s staging issued last iter -> Vs resident for PV below.
      __syncthreads();
      if (kt < qt) stageK(kt + 1);  // in flight under softmax + PV

      // ---- softmax ----
      float pm[4][4];
      bool diag = (kt == qt);
#pragma unroll
      for (int fn = 0; fn < 4; fn++)
#pragma unroll
        for (int r = 0; r < 4; r++) {
          float s = accs[fn][r] * 0.0625f;  // 1/sqrt(256); mask-before-scale == -1e30
          if (diag) {
            int kg = fn * 16 + c16;
            int qg = w * 16 + g4 * 4 + r;
            if (kg > qg) s = -1e30f;
          }
          pm[fn][r] = s;
        }
      float lmax[4];
#pragma unroll
      for (int r = 0; r < 4; r++)
        lmax[r] = fmaxf(fmaxf(pm[0][r], pm[1][r]), fmaxf(pm[2][r], pm[3][r]));
      bool need = false;
#pragma unroll
      for (int r = 0; r < 4; r++) need = need || (lmax[r] > mrow[r] + 8.0f);
      if (__any(need)) {  // rare: full max-reduce + rescale only here
#pragma unroll
        for (int r = 0; r < 4; r++) {
          float mx = lmax[r];
#pragma unroll
          for (int off = 1; off < 16; off <<= 1) mx = fmaxf(mx, __shfl_xor(mx, off));
          float mn = fmaxf(mrow[r], mx);
          float sc = __expf(mrow[r] - mn);
          mrow[r] = mn;
          lrow[r] *= sc;
#pragma unroll
          for (int fd = 0; fd < 16; fd++) acco[fd][r] *= sc;
        }
      }
#pragma unroll
      for (int fn = 0; fn < 4; fn++)
#pragma unroll
        for (int r = 0; r < 4; r++) {
          float p = __expf(pm[fn][r] - mrow[r]);
          pm[fn][r] = p;
          lrow[r] += p;
        }
#pragma unroll
      for (int fn = 0; fn < 4; fn++)
#pragma unroll
        for (int r = 0; r < 4; r++) {
          int q = g4 * 4 + r;
          int chunk = (fn * 2 + (c16 >> 3)) ^ (q & 7);
          Pl[w][q * 64 + chunk * 8 + (c16 & 7)] = (bf16)pm[fn][r];
        }
      // ---- PV(t) from Vs ----
      __builtin_amdgcn_s_setprio(1);
#pragma unroll
      for (int kk2 = 0; kk2 < 2; kk2++) {
        bf16x8 pf = *(const bf16x8*)(&Pl[w][c16 * 64 + ((kk2 * 4 + g4) ^ (c16 & 7)) * 8]);
#pragma unroll
        for (int fd = 0; fd < 16; fd++) {
          int rv = fd * 16 + c16;
          bf16x8 vf = *(const bf16x8*)(Vs + rv * 64 + ((kk2 * 4 + g4) ^ (c16 & 7)) * 8);
          acco[fd] = __builtin_amdgcn_mfma_f32_16x16x32_bf16(pf, vf, acco[fd], 0, 0, 0);
        }
      }
      __builtin_amdgcn_s_setprio(0);
      // barrier B: all PV reads of Vs done (frees Vs); implicit vmcnt(0)
      // drained K(t+1)'s staging -> Ks resident for next QK.
      __syncthreads();
      if (kt < qt) stageV(kt + 1);  // in flight under next QK
    }
    // epilogue: one row-wide sum-reduce of the per-lane lrow partials
    float inv[4];
#pragma unroll
    for (int r = 0; r < 4; r++) {
      float s = lrow[r];
#pragma unroll
      for (int off = 1; off < 16; off <<= 1) s += __shfl_xor(s, off);
      inv[r] = 1.0f / s;
    }
#pragma unroll
    for (int fd = 0; fd < 16; fd++)
#pragma unroll
      for (int r = 0; r < 4; r++) {
        int qg = q0w + g4 * 4 + r;
        int col = h * HDIM + fd * 16 + c16;
        O[(size_t)qg * EMBED + col] = (bf16)(acco[fd][r] * inv[r]);
      }
  }
}

extern "C" void kernel_launch(void* const* d_in, const int* in_sizes, int n_in,
                              void* d_out, int out_size, void* d_ws, size_t ws_size,
                              hipStream_t stream) {
  const float* hidden = (const float*)d_in[0];
  const float* Wq = (const float*)d_in[1];
  const float* Wk = (const float*)d_in[2];
  const float* Wv = (const float*)d_in[3];
  const float* Wo = (const float*)d_in[4];
  float* out = (float*)d_out;

  char* ws = (char*)d_ws;
  const size_t SZ_H = (size_t)SLEN * EMBED * 2;   // 16 MiB
  const size_t SZ_W = (size_t)EMBED * EMBED * 2;  // 32 MiB
  if (ws_size < 5 * SZ_H + SZ_W) return;

  bf16* h_bf = (bf16*)ws;
  bf16* Wt   = (bf16*)(ws + SZ_H);
  bf16* Qb   = (bf16*)(ws + SZ_H + SZ_W);
  bf16* Kb   = (bf16*)(ws + 2 * SZ_H + SZ_W);
  bf16* Vtb  = (bf16*)(ws + 3 * SZ_H + SZ_W);
  bf16* Ob   = (bf16*)(ws + 4 * SZ_H + SZ_W);

  cast_kernel<<<(SLEN * EMBED / 4 + 255) / 256, 256, 0, stream>>>(hidden, h_bf,
                                                                  SLEN * EMBED / 4);

  dim3 tgrid(EMBED / 64, EMBED / 64);
  dim3 ggrid(EMBED / 128, SLEN / 128);  // 32 x 16 = 512 blocks = 2/CU

  transpose_cast<<<tgrid, 256, 0, stream>>>(Wq, Wt);
  gemm_pipe<1><<<ggrid, 256, 0, stream>>>(h_bf, Wt, Qb, SLEN, EMBED, EMBED);

  transpose_cast<<<tgrid, 256, 0, stream>>>(Wk, Wt);
  gemm_pipe<1><<<ggrid, 256, 0, stream>>>(h_bf, Wt, Kb, SLEN, EMBED, EMBED);

  transpose_cast<<<tgrid, 256, 0, stream>>>(Wv, Wt);
  gemm_pipe<2><<<ggrid, 256, 0, stream>>>(h_bf, Wt, Vtb, SLEN, EMBED, EMBED);

  attn_kernel<<<dim3(256), 256, 0, stream>>>(Qb, Kb, Vtb, Ob);

  transpose_cast<<<tgrid, 256, 0, stream>>>(Wo, Wt);
  gemm_pipe<3><<<ggrid, 256, 0, stream>>>(Ob, Wt, out, SLEN, EMBED, EMBED);
}

// Round 15
// 459.658 us; speedup vs baseline: 1.0225x; 1.0225x over previous
//
#include <hip/hip_runtime.h>
#include <hip/hip_bf16.h>
#include <math.h>

#define EMBED 4096
#define SLEN 2048
#define HEADS 16
#define HDIM 256
#define ROT 64

typedef __bf16 bf16;
typedef __attribute__((ext_vector_type(8))) __bf16 bf16x8;
typedef __attribute__((ext_vector_type(4))) float f32x4;

__device__ __forceinline__ void async_copy16(const void* g, void* l) {
  __builtin_amdgcn_global_load_lds((const __attribute__((address_space(1))) void*)g,
                                   (__attribute__((address_space(3))) void*)l,
                                   16, 0, 0);
}

// ---------------- cast fp32 -> bf16 ----------------
__global__ __launch_bounds__(256) void cast_kernel(const float* __restrict__ in,
                                                   bf16* __restrict__ out, int n4) {
  int i = blockIdx.x * 256 + threadIdx.x;
  if (i >= n4) return;
  float4 v = ((const float4*)in)[i];
  bf16 o[4] __attribute__((aligned(8)));
  o[0] = (bf16)v.x; o[1] = (bf16)v.y; o[2] = (bf16)v.z; o[3] = (bf16)v.w;
  ((ushort4*)out)[i] = *(const ushort4*)o;
}

// ---------------- transpose + cast: Wt[n][k] = W[k][n] ----------------
__global__ __launch_bounds__(256) void transpose_cast(const float* __restrict__ W,
                                                      bf16* __restrict__ Wt) {
  __shared__ bf16 tile[64][65];
  int k0 = blockIdx.y * 64, n0 = blockIdx.x * 64;
  int tr = threadIdx.x >> 4, tc = threadIdx.x & 15;
#pragma unroll
  for (int i = 0; i < 4; i++) {
    int row = tr + i * 16;
    float4 v = *(const float4*)(W + (size_t)(k0 + row) * EMBED + n0 + tc * 4);
    tile[row][tc * 4 + 0] = (bf16)v.x;
    tile[row][tc * 4 + 1] = (bf16)v.y;
    tile[row][tc * 4 + 2] = (bf16)v.z;
    tile[row][tc * 4 + 3] = (bf16)v.w;
  }
  __syncthreads();
#pragma unroll
  for (int i = 0; i < 4; i++) {
    int nl = tr + i * 16;
    bf16 o[4] __attribute__((aligned(8)));
#pragma unroll
    for (int j = 0; j < 4; j++) o[j] = tile[tc * 4 + j][nl];
    *(ushort4*)(Wt + (size_t)(n0 + nl) * EMBED + k0 + tc * 4) = *(const ushort4*)o;
  }
}

// ---------------- pipelined GEMM: C[M,N] = A[M,K] * Bt[N,K]^T (bf16 in) -------
// R13-PROVEN (best measured): BM=128, BN=256, BK=64; 512 threads = 8 waves
// (2M x 4N), 64x64 per wave. Triple-buffered LDS (144 KB), prefetch depth 2,
// ONE barrier per K-tile, counted vmcnt(6) (T3+T4), XOR swizzle (T2,
// conflicts=0). R14's 128^2 2-block/CU variant was neutral-to-worse — revert.
// MODE 1: rotary out (Q,K); 2: V-transposed; 3: fp32.
template <int MODE>
__global__ __launch_bounds__(512, 1) void gemm_pipe(const bf16* __restrict__ A,
                                                    const bf16* __restrict__ Bt,
                                                    void* __restrict__ Cout,
                                                    int M, int N, int K) {
  constexpr int BM = 128, BN = 256, BK = 64;
  __shared__ __align__(16) bf16 As[3][BM * BK];  // 3 x 16 KB
  __shared__ __align__(16) bf16 Bs[3][BN * BK];  // 3 x 32 KB
  int t = threadIdx.x;
  int lane = t & 63, w = t >> 6;
  int c16 = lane & 15, g4 = lane >> 4;
  int wm = w >> 2, wn = w & 3;
  int m0 = blockIdx.y * BM, n0 = blockIdx.x * BN;
  int nt = K / BK;

  f32x4 acc[4][4] = {};

  auto stage = [&](int kt, int slot) {
    const bf16* Asrc = A + (size_t)m0 * K + kt * BK;
    const bf16* Bsrc = Bt + (size_t)n0 * K + kt * BK;
    bf16* Ad = As[slot];
    bf16* Bd = Bs[slot];
#pragma unroll
    for (int i = 0; i < 2; i++) {  // A: 1024 chunks / 512 threads
      int c = i * 512 + t;
      int row = c >> 3, col8 = c & 7;
      async_copy16(Asrc + (size_t)row * K + ((col8 ^ (row & 7)) * 8), Ad + c * 8);
    }
#pragma unroll
    for (int i = 0; i < 4; i++) {  // B: 2048 chunks / 512 threads
      int c = i * 512 + t;
      int row = c >> 3, col8 = c & 7;
      async_copy16(Bsrc + (size_t)row * K + ((col8 ^ (row & 7)) * 8), Bd + c * 8);
    }
  };

  // prologue: tiles 0 and 1 in flight; wait tile 0 (6 of 12 outstanding left)
  stage(0, 0);
  stage(1, 1);
  asm volatile("s_waitcnt vmcnt(6)" ::: "memory");
  __builtin_amdgcn_s_barrier();

  for (int kt = 0; kt < nt; kt++) {
    int slot = kt - (kt / 3) * 3;
    const bf16* Ab = As[slot];
    const bf16* Bb = Bs[slot];

    // issue ALL fragment reads for this tile up front (kk0 then kk1); the
    // compiler's counted lgkmcnt lets kk1's reads complete under kk0's MFMAs.
    bf16x8 af[2][4], bfr[2][4];
#pragma unroll
    for (int kk = 0; kk < 2; kk++) {
#pragma unroll
      for (int fm = 0; fm < 4; fm++) {
        int row = wm * 64 + fm * 16 + c16;
        af[kk][fm] = *(const bf16x8*)(Ab + row * BK + (((kk * 4 + g4) ^ (row & 7)) * 8));
      }
#pragma unroll
      for (int fn = 0; fn < 4; fn++) {
        int row = wn * 64 + fn * 16 + c16;
        bfr[kk][fn] = *(const bf16x8*)(Bb + row * BK + (((kk * 4 + g4) ^ (row & 7)) * 8));
      }
    }
    if (kt + 2 < nt) {
      int s2 = (kt + 2) - ((kt + 2) / 3) * 3;
      stage(kt + 2, s2);
    }
    __builtin_amdgcn_s_setprio(1);
#pragma unroll
    for (int kk = 0; kk < 2; kk++)
#pragma unroll
      for (int fm = 0; fm < 4; fm++)
#pragma unroll
        for (int fn = 0; fn < 4; fn++)
          acc[fm][fn] = __builtin_amdgcn_mfma_f32_16x16x32_bf16(af[kk][fm], bfr[kk][fn],
                                                                acc[fm][fn], 0, 0, 0);
    __builtin_amdgcn_s_setprio(0);
    // end-of-tile sync: tile kt+1 must be resident; tile kt+2 stays in flight.
    if (kt < nt - 2) {
      asm volatile("s_waitcnt vmcnt(6)" ::: "memory");
      __builtin_amdgcn_s_barrier();
    } else if (kt == nt - 2) {
      asm volatile("s_waitcnt vmcnt(0)" ::: "memory");
      __builtin_amdgcn_s_barrier();
    }
  }

  // epilogue
#pragma unroll
  for (int fm = 0; fm < 4; fm++) {
#pragma unroll
    for (int fn = 0; fn < 4; fn++) {
      int col = n0 + wn * 64 + fn * 16 + c16;
#pragma unroll
      for (int r = 0; r < 4; r++) {
        int row = m0 + wm * 64 + fm * 16 + g4 * 4 + r;
        float v = acc[fm][fn][r];
        if (MODE == 1) {
          int d = col & (HDIM - 1);
          if (d < ROT) {  // wave-uniform: true iff wn==0
            float pv = __shfl_xor(v, 1);
            int jj = d >> 1;
            float invf = __expf(-0.28782313662425575f * (float)jj);
            float ang = (float)row * invf;
            float sa, ca;
            sincosf(ang, &sa, &ca);
            v = v * ca + pv * sa;  // reference has NO negation in rotate_every_two
          }
        }
        if (MODE == 3) {
          ((float*)Cout)[(size_t)row * N + col] = v;
        } else if (MODE == 2) {
          ((bf16*)Cout)[(size_t)col * M + row] = (bf16)v;
        } else {
          ((bf16*)Cout)[(size_t)row * N + col] = (bf16)v;
        }
      }
    }
  }
}

// ---------------- causal flash attention (ping-pong K/V, 512 blocks) ----------
// R15: EXACT R13 inner loop; grid change only. 512 blocks = one q-tile each,
// LPT order qt = 31-(b>>4) (heavy first; with 2 blocks/CU the scheduler
// backfills — the slot R7 lacked). h = (b&7)*2+((b>>3)&1): 2 heads/XCD (K+V
// = 4 MB = one L2). LDS 72 KB -> 2 blocks/CU: the co-resident block's QK/PV
// covers this block's softmax/staging bubbles (cross-block TLP — R13's 72 KB
// shrink finally pays; at 256 blocks it never got a sibling).
// Ping-pong: QK(t) | barrier A | stage K(t+1) | softmax | PV(t) | barrier B |
// stage V(t+1). XOR-swizzled LDS, defer-max (T13), per-lane lrow (R11).
__global__ __launch_bounds__(256, 2) void attn_kernel(const bf16* __restrict__ Q,
                                                      const bf16* __restrict__ Kmat,
                                                      const bf16* __restrict__ Vt,
                                                      bf16* __restrict__ O) {
  __shared__ __align__(16) bf16 Ks[64 * 256];   // [kv_row][d], swizzled (32 KB)
  __shared__ __align__(16) bf16 Vs[64 * 256];   // [d][kv_row], swizzled (32 KB)
  __shared__ __align__(16) bf16 Pl[4][16 * 64]; // per-wave P, swizzled (8 KB)
  int t = threadIdx.x, lane = t & 63, w = t >> 6;
  int c16 = lane & 15, g4 = lane >> 4;
  int b = blockIdx.x;
  int h = ((b & 7) << 1) | ((b >> 3) & 1);
  int qt = 31 - (b >> 4);  // LPT: heavy q-tiles dispatch first
  int q0w = qt * 64 + w * 16;

  auto stageK = [&](int kt) {
#pragma unroll
    for (int j = 0; j < 8; j++) {
      int c = j * 256 + t;
      int row = c >> 5, col8 = c & 31;
      async_copy16(Kmat + (size_t)(kt * 64 + row) * EMBED + h * HDIM +
                       ((col8 ^ (row & 7)) * 8),
                   Ks + (size_t)c * 8);
    }
  };
  auto stageV = [&](int kt) {
#pragma unroll
    for (int j = 0; j < 8; j++) {
      int c = j * 256 + t;
      int row = c >> 3, col8 = c & 7;
      async_copy16(Vt + (size_t)(h * HDIM + row) * SLEN + kt * 64 +
                       ((col8 ^ (row & 7)) * 8),
                   Vs + (size_t)c * 8);
    }
  };

  bf16x8 qf[8];
  {
    const bf16* qp = Q + (size_t)(q0w + c16) * EMBED + h * HDIM + g4 * 8;
#pragma unroll
    for (int kk = 0; kk < 8; kk++) qf[kk] = *(const bf16x8*)(qp + kk * 32);
  }
  f32x4 acco[16] = {};
  float mrow[4], lrow[4];  // mrow row-uniform; lrow PER-LANE partial
#pragma unroll
  for (int r = 0; r < 4; r++) { mrow[r] = -1e30f; lrow[r] = 0.f; }

  stageK(0);
  stageV(0);
  __syncthreads();  // drain: K(0), V(0) resident

  for (int kt = 0; kt <= qt; kt++) {
    // ---- QK(t) from Ks ----
    f32x4 accs[4] = {};
    __builtin_amdgcn_s_setprio(1);
#pragma unroll
    for (int kk = 0; kk < 8; kk++) {
#pragma unroll
      for (int fn = 0; fn < 4; fn++) {
        int r = fn * 16 + c16;
        bf16x8 kf = *(const bf16x8*)(Ks + r * 256 + ((kk * 4 + g4) ^ (c16 & 7)) * 8);
        accs[fn] = __builtin_amdgcn_mfma_f32_16x16x32_bf16(qf[kk], kf, accs[fn], 0, 0, 0);
      }
    }
    __builtin_amdgcn_s_setprio(0);
    // barrier A: all QK reads of Ks done (frees Ks); implicit vmcnt(0)
    // drained V(t)'s staging issued last iter -> Vs resident for PV below.
    __syncthreads();
    if (kt < qt) stageK(kt + 1);  // in flight under softmax + PV

    // ---- softmax ----
    float pm[4][4];
    bool diag = (kt == qt);
#pragma unroll
    for (int fn = 0; fn < 4; fn++)
#pragma unroll
      for (int r = 0; r < 4; r++) {
        float s = accs[fn][r] * 0.0625f;  // 1/sqrt(256); mask-before-scale == -1e30
        if (diag) {
          int kg = fn * 16 + c16;
          int qg = w * 16 + g4 * 4 + r;
          if (kg > qg) s = -1e30f;
        }
        pm[fn][r] = s;
      }
    float lmax[4];
#pragma unroll
    for (int r = 0; r < 4; r++)
      lmax[r] = fmaxf(fmaxf(pm[0][r], pm[1][r]), fmaxf(pm[2][r], pm[3][r]));
    bool need = false;
#pragma unroll
    for (int r = 0; r < 4; r++) need = need || (lmax[r] > mrow[r] + 8.0f);
    if (__any(need)) {  // rare: full max-reduce + rescale only here
#pragma unroll
      for (int r = 0; r < 4; r++) {
        float mx = lmax[r];
#pragma unroll
        for (int off = 1; off < 16; off <<= 1) mx = fmaxf(mx, __shfl_xor(mx, off));
        float mn = fmaxf(mrow[r], mx);
        float sc = __expf(mrow[r] - mn);
        mrow[r] = mn;
        lrow[r] *= sc;
#pragma unroll
        for (int fd = 0; fd < 16; fd++) acco[fd][r] *= sc;
      }
    }
#pragma unroll
    for (int fn = 0; fn < 4; fn++)
#pragma unroll
      for (int r = 0; r < 4; r++) {
        float p = __expf(pm[fn][r] - mrow[r]);
        pm[fn][r] = p;
        lrow[r] += p;
      }
#pragma unroll
    for (int fn = 0; fn < 4; fn++)
#pragma unroll
      for (int r = 0; r < 4; r++) {
        int q = g4 * 4 + r;
        int chunk = (fn * 2 + (c16 >> 3)) ^ (q & 7);
        Pl[w][q * 64 + chunk * 8 + (c16 & 7)] = (bf16)pm[fn][r];
      }
    // ---- PV(t) from Vs ----
    __builtin_amdgcn_s_setprio(1);
#pragma unroll
    for (int kk2 = 0; kk2 < 2; kk2++) {
      bf16x8 pf = *(const bf16x8*)(&Pl[w][c16 * 64 + ((kk2 * 4 + g4) ^ (c16 & 7)) * 8]);
#pragma unroll
      for (int fd = 0; fd < 16; fd++) {
        int rv = fd * 16 + c16;
        bf16x8 vf = *(const bf16x8*)(Vs + rv * 64 + ((kk2 * 4 + g4) ^ (c16 & 7)) * 8);
        acco[fd] = __builtin_amdgcn_mfma_f32_16x16x32_bf16(pf, vf, acco[fd], 0, 0, 0);
      }
    }
    __builtin_amdgcn_s_setprio(0);
    // barrier B: all PV reads of Vs done (frees Vs); implicit vmcnt(0)
    // drained K(t+1)'s staging -> Ks resident for next QK.
    __syncthreads();
    if (kt < qt) stageV(kt + 1);  // in flight under next QK
  }
  // epilogue: one row-wide sum-reduce of the per-lane lrow partials
  float inv[4];
#pragma unroll
  for (int r = 0; r < 4; r++) {
    float s = lrow[r];
#pragma unroll
    for (int off = 1; off < 16; off <<= 1) s += __shfl_xor(s, off);
    inv[r] = 1.0f / s;
  }
#pragma unroll
  for (int fd = 0; fd < 16; fd++)
#pragma unroll
    for (int r = 0; r < 4; r++) {
      int qg = q0w + g4 * 4 + r;
      int col = h * HDIM + fd * 16 + c16;
      O[(size_t)qg * EMBED + col] = (bf16)(acco[fd][r] * inv[r]);
    }
}

extern "C" void kernel_launch(void* const* d_in, const int* in_sizes, int n_in,
                              void* d_out, int out_size, void* d_ws, size_t ws_size,
                              hipStream_t stream) {
  const float* hidden = (const float*)d_in[0];
  const float* Wq = (const float*)d_in[1];
  const float* Wk = (const float*)d_in[2];
  const float* Wv = (const float*)d_in[3];
  const float* Wo = (const float*)d_in[4];
  float* out = (float*)d_out;

  char* ws = (char*)d_ws;
  const size_t SZ_H = (size_t)SLEN * EMBED * 2;   // 16 MiB
  const size_t SZ_W = (size_t)EMBED * EMBED * 2;  // 32 MiB
  if (ws_size < 5 * SZ_H + SZ_W) return;

  bf16* h_bf = (bf16*)ws;
  bf16* Wt   = (bf16*)(ws + SZ_H);
  bf16* Qb   = (bf16*)(ws + SZ_H + SZ_W);
  bf16* Kb   = (bf16*)(ws + 2 * SZ_H + SZ_W);
  bf16* Vtb  = (bf16*)(ws + 3 * SZ_H + SZ_W);
  bf16* Ob   = (bf16*)(ws + 4 * SZ_H + SZ_W);

  cast_kernel<<<(SLEN * EMBED / 4 + 255) / 256, 256, 0, stream>>>(hidden, h_bf,
                                                                  SLEN * EMBED / 4);

  dim3 tgrid(EMBED / 64, EMBED / 64);
  dim3 ggrid(EMBED / 256, SLEN / 128);  // 16 x 16 = 256 blocks

  transpose_cast<<<tgrid, 256, 0, stream>>>(Wq, Wt);
  gemm_pipe<1><<<ggrid, 512, 0, stream>>>(h_bf, Wt, Qb, SLEN, EMBED, EMBED);

  transpose_cast<<<tgrid, 256, 0, stream>>>(Wk, Wt);
  gemm_pipe<1><<<ggrid, 512, 0, stream>>>(h_bf, Wt, Kb, SLEN, EMBED, EMBED);

  transpose_cast<<<tgrid, 256, 0, stream>>>(Wv, Wt);
  gemm_pipe<2><<<ggrid, 512, 0, stream>>>(h_bf, Wt, Vtb, SLEN, EMBED, EMBED);

  attn_kernel<<<dim3(512), 256, 0, stream>>>(Qb, Kb, Vtb, Ob);

  transpose_cast<<<tgrid, 256, 0, stream>>>(Wo, Wt);
  gemm_pipe<3><<<ggrid, 512, 0, stream>>>(Ob, Wt, out, SLEN, EMBED, EMBED);
}

// Round 16
// 453.324 us; speedup vs baseline: 1.0368x; 1.0140x over previous
//
#include <hip/hip_runtime.h>
#include <hip/hip_bf16.h>
#include <math.h>

#define EMBED 4096
#define SLEN 2048
#define HEADS 16
#define HDIM 256
#define ROT 64

typedef __bf16 bf16;
typedef __attribute__((ext_vector_type(8))) __bf16 bf16x8;
typedef __attribute__((ext_vector_type(4))) float f32x4;

__device__ __forceinline__ void async_copy16(const void* g, void* l) {
  __builtin_amdgcn_global_load_lds((const __attribute__((address_space(1))) void*)g,
                                   (__attribute__((address_space(3))) void*)l,
                                   16, 0, 0);
}

// ---------------- cast fp32 -> bf16 ----------------
__global__ __launch_bounds__(256) void cast_kernel(const float* __restrict__ in,
                                                   bf16* __restrict__ out, int n4) {
  int i = blockIdx.x * 256 + threadIdx.x;
  if (i >= n4) return;
  float4 v = ((const float4*)in)[i];
  bf16 o[4] __attribute__((aligned(8)));
  o[0] = (bf16)v.x; o[1] = (bf16)v.y; o[2] = (bf16)v.z; o[3] = (bf16)v.w;
  ((ushort4*)out)[i] = *(const ushort4*)o;
}

// ---------------- transpose + cast: Wt[n][k] = W[k][n] ----------------
__global__ __launch_bounds__(256) void transpose_cast(const float* __restrict__ W,
                                                      bf16* __restrict__ Wt) {
  __shared__ bf16 tile[64][65];
  int k0 = blockIdx.y * 64, n0 = blockIdx.x * 64;
  int tr = threadIdx.x >> 4, tc = threadIdx.x & 15;
#pragma unroll
  for (int i = 0; i < 4; i++) {
    int row = tr + i * 16;
    float4 v = *(const float4*)(W + (size_t)(k0 + row) * EMBED + n0 + tc * 4);
    tile[row][tc * 4 + 0] = (bf16)v.x;
    tile[row][tc * 4 + 1] = (bf16)v.y;
    tile[row][tc * 4 + 2] = (bf16)v.z;
    tile[row][tc * 4 + 3] = (bf16)v.w;
  }
  __syncthreads();
#pragma unroll
  for (int i = 0; i < 4; i++) {
    int nl = tr + i * 16;
    bf16 o[4] __attribute__((aligned(8)));
#pragma unroll
    for (int j = 0; j < 4; j++) o[j] = tile[tc * 4 + j][nl];
    *(ushort4*)(Wt + (size_t)(n0 + nl) * EMBED + k0 + tc * 4) = *(const ushort4*)o;
  }
}

// ---------------- pipelined GEMM: C[M,N] = A[M,K] * Bt[N,K]^T (bf16 in) -------
// R13-PROVEN (best measured): BM=128, BN=256, BK=64; 512 threads = 8 waves
// (2M x 4N), 64x64 per wave. Triple-buffered LDS (144 KB), prefetch depth 2,
// ONE barrier per K-tile, counted vmcnt(6) (T3+T4), XOR swizzle (T2,
// conflicts=0). MODE 1: rotary out (Q,K); 2: V-transposed; 3: fp32.
template <int MODE>
__global__ __launch_bounds__(512, 1) void gemm_pipe(const bf16* __restrict__ A,
                                                    const bf16* __restrict__ Bt,
                                                    void* __restrict__ Cout,
                                                    int M, int N, int K) {
  constexpr int BM = 128, BN = 256, BK = 64;
  __shared__ __align__(16) bf16 As[3][BM * BK];  // 3 x 16 KB
  __shared__ __align__(16) bf16 Bs[3][BN * BK];  // 3 x 32 KB
  int t = threadIdx.x;
  int lane = t & 63, w = t >> 6;
  int c16 = lane & 15, g4 = lane >> 4;
  int wm = w >> 2, wn = w & 3;
  int m0 = blockIdx.y * BM, n0 = blockIdx.x * BN;
  int nt = K / BK;

  f32x4 acc[4][4] = {};

  auto stage = [&](int kt, int slot) {
    const bf16* Asrc = A + (size_t)m0 * K + kt * BK;
    const bf16* Bsrc = Bt + (size_t)n0 * K + kt * BK;
    bf16* Ad = As[slot];
    bf16* Bd = Bs[slot];
#pragma unroll
    for (int i = 0; i < 2; i++) {  // A: 1024 chunks / 512 threads
      int c = i * 512 + t;
      int row = c >> 3, col8 = c & 7;
      async_copy16(Asrc + (size_t)row * K + ((col8 ^ (row & 7)) * 8), Ad + c * 8);
    }
#pragma unroll
    for (int i = 0; i < 4; i++) {  // B: 2048 chunks / 512 threads
      int c = i * 512 + t;
      int row = c >> 3, col8 = c & 7;
      async_copy16(Bsrc + (size_t)row * K + ((col8 ^ (row & 7)) * 8), Bd + c * 8);
    }
  };

  // prologue: tiles 0 and 1 in flight; wait tile 0 (6 of 12 outstanding left)
  stage(0, 0);
  stage(1, 1);
  asm volatile("s_waitcnt vmcnt(6)" ::: "memory");
  __builtin_amdgcn_s_barrier();

  for (int kt = 0; kt < nt; kt++) {
    int slot = kt - (kt / 3) * 3;
    const bf16* Ab = As[slot];
    const bf16* Bb = Bs[slot];

    // issue ALL fragment reads for this tile up front (kk0 then kk1); the
    // compiler's counted lgkmcnt lets kk1's reads complete under kk0's MFMAs.
    bf16x8 af[2][4], bfr[2][4];
#pragma unroll
    for (int kk = 0; kk < 2; kk++) {
#pragma unroll
      for (int fm = 0; fm < 4; fm++) {
        int row = wm * 64 + fm * 16 + c16;
        af[kk][fm] = *(const bf16x8*)(Ab + row * BK + (((kk * 4 + g4) ^ (row & 7)) * 8));
      }
#pragma unroll
      for (int fn = 0; fn < 4; fn++) {
        int row = wn * 64 + fn * 16 + c16;
        bfr[kk][fn] = *(const bf16x8*)(Bb + row * BK + (((kk * 4 + g4) ^ (row & 7)) * 8));
      }
    }
    if (kt + 2 < nt) {
      int s2 = (kt + 2) - ((kt + 2) / 3) * 3;
      stage(kt + 2, s2);
    }
    __builtin_amdgcn_s_setprio(1);
#pragma unroll
    for (int kk = 0; kk < 2; kk++)
#pragma unroll
      for (int fm = 0; fm < 4; fm++)
#pragma unroll
        for (int fn = 0; fn < 4; fn++)
          acc[fm][fn] = __builtin_amdgcn_mfma_f32_16x16x32_bf16(af[kk][fm], bfr[kk][fn],
                                                                acc[fm][fn], 0, 0, 0);
    __builtin_amdgcn_s_setprio(0);
    // end-of-tile sync: tile kt+1 must be resident; tile kt+2 stays in flight.
    if (kt < nt - 2) {
      asm volatile("s_waitcnt vmcnt(6)" ::: "memory");
      __builtin_amdgcn_s_barrier();
    } else if (kt == nt - 2) {
      asm volatile("s_waitcnt vmcnt(0)" ::: "memory");
      __builtin_amdgcn_s_barrier();
    }
  }

  // epilogue
#pragma unroll
  for (int fm = 0; fm < 4; fm++) {
#pragma unroll
    for (int fn = 0; fn < 4; fn++) {
      int col = n0 + wn * 64 + fn * 16 + c16;
#pragma unroll
      for (int r = 0; r < 4; r++) {
        int row = m0 + wm * 64 + fm * 16 + g4 * 4 + r;
        float v = acc[fm][fn][r];
        if (MODE == 1) {
          int d = col & (HDIM - 1);
          if (d < ROT) {  // wave-uniform: true iff wn==0
            float pv = __shfl_xor(v, 1);
            int jj = d >> 1;
            float invf = __expf(-0.28782313662425575f * (float)jj);
            float ang = (float)row * invf;
            float sa, ca;
            sincosf(ang, &sa, &ca);
            v = v * ca + pv * sa;  // reference has NO negation in rotate_every_two
          }
        }
        if (MODE == 3) {
          ((float*)Cout)[(size_t)row * N + col] = v;
        } else if (MODE == 2) {
          ((bf16*)Cout)[(size_t)col * M + row] = (bf16)v;
        } else {
          ((bf16*)Cout)[(size_t)row * N + col] = (bf16)v;
        }
      }
    }
  }
}

// ---------------- causal flash attention (ping-pong K/V, balanced 512) --------
// R16: EXACT R13/R15 inner loop; only the block->(h,qt) map changed.
// 512 blocks, 2/CU. Under round-robin dispatch the co-resident pair on a CU is
// ~(b, b+256). Map: b<256 -> qt=31-(b>>4) (heavy, 17..32 iters); b>=256 ->
// qt=(b-256)>>4 (light, 1..16 iters). Pair sum = 33 iters on EVERY CU
// (R15's map summed 18..48 — the imbalance cancelled the TLP win). The pair
// also shares h = b&15 -> same K/V lines in L2; h in {xcd, xcd+8} keeps
// 2 heads/XCD. Ping-pong: QK(t) | barrier A | stage K(t+1) | softmax | PV(t) |
// barrier B | stage V(t+1). XOR-swizzle, defer-max (T13), per-lane lrow (R11).
__global__ __launch_bounds__(256, 2) void attn_kernel(const bf16* __restrict__ Q,
                                                      const bf16* __restrict__ Kmat,
                                                      const bf16* __restrict__ Vt,
                                                      bf16* __restrict__ O) {
  __shared__ __align__(16) bf16 Ks[64 * 256];   // [kv_row][d], swizzled (32 KB)
  __shared__ __align__(16) bf16 Vs[64 * 256];   // [d][kv_row], swizzled (32 KB)
  __shared__ __align__(16) bf16 Pl[4][16 * 64]; // per-wave P, swizzled (8 KB)
  int t = threadIdx.x, lane = t & 63, w = t >> 6;
  int c16 = lane & 15, g4 = lane >> 4;
  int b = blockIdx.x;
  int bb = b & 255;
  int h = bb & 15;
  int k = bb >> 4;                       // 0..15
  int qt = (b >> 8) ? k : (31 - k);      // heavy half first; pair sums to 33
  int q0w = qt * 64 + w * 16;

  auto stageK = [&](int kt) {
#pragma unroll
    for (int j = 0; j < 8; j++) {
      int c = j * 256 + t;
      int row = c >> 5, col8 = c & 31;
      async_copy16(Kmat + (size_t)(kt * 64 + row) * EMBED + h * HDIM +
                       ((col8 ^ (row & 7)) * 8),
                   Ks + (size_t)c * 8);
    }
  };
  auto stageV = [&](int kt) {
#pragma unroll
    for (int j = 0; j < 8; j++) {
      int c = j * 256 + t;
      int row = c >> 3, col8 = c & 7;
      async_copy16(Vt + (size_t)(h * HDIM + row) * SLEN + kt * 64 +
                       ((col8 ^ (row & 7)) * 8),
                   Vs + (size_t)c * 8);
    }
  };

  bf16x8 qf[8];
  {
    const bf16* qp = Q + (size_t)(q0w + c16) * EMBED + h * HDIM + g4 * 8;
#pragma unroll
    for (int kk = 0; kk < 8; kk++) qf[kk] = *(const bf16x8*)(qp + kk * 32);
  }
  f32x4 acco[16] = {};
  float mrow[4], lrow[4];  // mrow row-uniform; lrow PER-LANE partial
#pragma unroll
  for (int r = 0; r < 4; r++) { mrow[r] = -1e30f; lrow[r] = 0.f; }

  stageK(0);
  stageV(0);
  __syncthreads();  // drain: K(0), V(0) resident

  for (int kt = 0; kt <= qt; kt++) {
    // ---- QK(t) from Ks ----
    f32x4 accs[4] = {};
    __builtin_amdgcn_s_setprio(1);
#pragma unroll
    for (int kk = 0; kk < 8; kk++) {
#pragma unroll
      for (int fn = 0; fn < 4; fn++) {
        int r = fn * 16 + c16;
        bf16x8 kf = *(const bf16x8*)(Ks + r * 256 + ((kk * 4 + g4) ^ (c16 & 7)) * 8);
        accs[fn] = __builtin_amdgcn_mfma_f32_16x16x32_bf16(qf[kk], kf, accs[fn], 0, 0, 0);
      }
    }
    __builtin_amdgcn_s_setprio(0);
    // barrier A: all QK reads of Ks done (frees Ks); implicit vmcnt(0)
    // drained V(t)'s staging issued last iter -> Vs resident for PV below.
    __syncthreads();
    if (kt < qt) stageK(kt + 1);  // in flight under softmax + PV

    // ---- softmax ----
    float pm[4][4];
    bool diag = (kt == qt);
#pragma unroll
    for (int fn = 0; fn < 4; fn++)
#pragma unroll
      for (int r = 0; r < 4; r++) {
        float s = accs[fn][r] * 0.0625f;  // 1/sqrt(256); mask-before-scale == -1e30
        if (diag) {
          int kg = fn * 16 + c16;
          int qg = w * 16 + g4 * 4 + r;
          if (kg > qg) s = -1e30f;
        }
        pm[fn][r] = s;
      }
    float lmax[4];
#pragma unroll
    for (int r = 0; r < 4; r++)
      lmax[r] = fmaxf(fmaxf(pm[0][r], pm[1][r]), fmaxf(pm[2][r], pm[3][r]));
    bool need = false;
#pragma unroll
    for (int r = 0; r < 4; r++) need = need || (lmax[r] > mrow[r] + 8.0f);
    if (__any(need)) {  // rare: full max-reduce + rescale only here
#pragma unroll
      for (int r = 0; r < 4; r++) {
        float mx = lmax[r];
#pragma unroll
        for (int off = 1; off < 16; off <<= 1) mx = fmaxf(mx, __shfl_xor(mx, off));
        float mn = fmaxf(mrow[r], mx);
        float sc = __expf(mrow[r] - mn);
        mrow[r] = mn;
        lrow[r] *= sc;
#pragma unroll
        for (int fd = 0; fd < 16; fd++) acco[fd][r] *= sc;
      }
    }
#pragma unroll
    for (int fn = 0; fn < 4; fn++)
#pragma unroll
      for (int r = 0; r < 4; r++) {
        float p = __expf(pm[fn][r] - mrow[r]);
        pm[fn][r] = p;
        lrow[r] += p;
      }
#pragma unroll
    for (int fn = 0; fn < 4; fn++)
#pragma unroll
      for (int r = 0; r < 4; r++) {
        int q = g4 * 4 + r;
        int chunk = (fn * 2 + (c16 >> 3)) ^ (q & 7);
        Pl[w][q * 64 + chunk * 8 + (c16 & 7)] = (bf16)pm[fn][r];
      }
    // ---- PV(t) from Vs ----
    __builtin_amdgcn_s_setprio(1);
#pragma unroll
    for (int kk2 = 0; kk2 < 2; kk2++) {
      bf16x8 pf = *(const bf16x8*)(&Pl[w][c16 * 64 + ((kk2 * 4 + g4) ^ (c16 & 7)) * 8]);
#pragma unroll
      for (int fd = 0; fd < 16; fd++) {
        int rv = fd * 16 + c16;
        bf16x8 vf = *(const bf16x8*)(Vs + rv * 64 + ((kk2 * 4 + g4) ^ (c16 & 7)) * 8);
        acco[fd] = __builtin_amdgcn_mfma_f32_16x16x32_bf16(pf, vf, acco[fd], 0, 0, 0);
      }
    }
    __builtin_amdgcn_s_setprio(0);
    // barrier B: all PV reads of Vs done (frees Vs); implicit vmcnt(0)
    // drained K(t+1)'s staging -> Ks resident for next QK.
    __syncthreads();
    if (kt < qt) stageV(kt + 1);  // in flight under next QK
  }
  // epilogue: one row-wide sum-reduce of the per-lane lrow partials
  float inv[4];
#pragma unroll
  for (int r = 0; r < 4; r++) {
    float s = lrow[r];
#pragma unroll
    for (int off = 1; off < 16; off <<= 1) s += __shfl_xor(s, off);
    inv[r] = 1.0f / s;
  }
#pragma unroll
  for (int fd = 0; fd < 16; fd++)
#pragma unroll
    for (int r = 0; r < 4; r++) {
      int qg = q0w + g4 * 4 + r;
      int col = h * HDIM + fd * 16 + c16;
      O[(size_t)qg * EMBED + col] = (bf16)(acco[fd][r] * inv[r]);
    }
}

extern "C" void kernel_launch(void* const* d_in, const int* in_sizes, int n_in,
                              void* d_out, int out_size, void* d_ws, size_t ws_size,
                              hipStream_t stream) {
  const float* hidden = (const float*)d_in[0];
  const float* Wq = (const float*)d_in[1];
  const float* Wk = (const float*)d_in[2];
  const float* Wv = (const float*)d_in[3];
  const float* Wo = (const float*)d_in[4];
  float* out = (float*)d_out;

  char* ws = (char*)d_ws;
  const size_t SZ_H = (size_t)SLEN * EMBED * 2;   // 16 MiB
  const size_t SZ_W = (size_t)EMBED * EMBED * 2;  // 32 MiB
  if (ws_size < 5 * SZ_H + SZ_W) return;

  bf16* h_bf = (bf16*)ws;
  bf16* Wt   = (bf16*)(ws + SZ_H);
  bf16* Qb   = (bf16*)(ws + SZ_H + SZ_W);
  bf16* Kb   = (bf16*)(ws + 2 * SZ_H + SZ_W);
  bf16* Vtb  = (bf16*)(ws + 3 * SZ_H + SZ_W);
  bf16* Ob   = (bf16*)(ws + 4 * SZ_H + SZ_W);

  cast_kernel<<<(SLEN * EMBED / 4 + 255) / 256, 256, 0, stream>>>(hidden, h_bf,
                                                                  SLEN * EMBED / 4);

  dim3 tgrid(EMBED / 64, EMBED / 64);
  dim3 ggrid(EMBED / 256, SLEN / 128);  // 16 x 16 = 256 blocks

  transpose_cast<<<tgrid, 256, 0, stream>>>(Wq, Wt);
  gemm_pipe<1><<<ggrid, 512, 0, stream>>>(h_bf, Wt, Qb, SLEN, EMBED, EMBED);

  transpose_cast<<<tgrid, 256, 0, stream>>>(Wk, Wt);
  gemm_pipe<1><<<ggrid, 512, 0, stream>>>(h_bf, Wt, Kb, SLEN, EMBED, EMBED);

  transpose_cast<<<tgrid, 256, 0, stream>>>(Wv, Wt);
  gemm_pipe<2><<<ggrid, 512, 0, stream>>>(h_bf, Wt, Vtb, SLEN, EMBED, EMBED);

  attn_kernel<<<dim3(512), 256, 0, stream>>>(Qb, Kb, Vtb, Ob);

  transpose_cast<<<tgrid, 256, 0, stream>>>(Wo, Wt);
  gemm_pipe<3><<<ggrid, 512, 0, stream>>>(Ob, Wt, out, SLEN, EMBED, EMBED);
}

// Round 17
// 450.456 us; speedup vs baseline: 1.0434x; 1.0064x over previous
//
#include <hip/hip_runtime.h>
#include <hip/hip_bf16.h>
#include <math.h>

#define EMBED 4096
#define SLEN 2048
#define HEADS 16
#define HDIM 256
#define ROT 64

typedef __bf16 bf16;
typedef __attribute__((ext_vector_type(8))) __bf16 bf16x8;
typedef __attribute__((ext_vector_type(4))) float f32x4;

__device__ __forceinline__ void async_copy16(const void* g, void* l) {
  __builtin_amdgcn_global_load_lds((const __attribute__((address_space(1))) void*)g,
                                   (__attribute__((address_space(3))) void*)l,
                                   16, 0, 0);
}

// ---------------- cast fp32 -> bf16 ----------------
__global__ __launch_bounds__(256) void cast_kernel(const float* __restrict__ in,
                                                   bf16* __restrict__ out, int n4) {
  int i = blockIdx.x * 256 + threadIdx.x;
  if (i >= n4) return;
  float4 v = ((const float4*)in)[i];
  bf16 o[4] __attribute__((aligned(8)));
  o[0] = (bf16)v.x; o[1] = (bf16)v.y; o[2] = (bf16)v.z; o[3] = (bf16)v.w;
  ((ushort4*)out)[i] = *(const ushort4*)o;
}

// ---------------- transpose + cast: Wt[n][k] = W[k][n] ----------------
__device__ __forceinline__ void transpose_body(const float* __restrict__ W,
                                               bf16* __restrict__ Wt) {
  __shared__ bf16 tile[64][65];
  int k0 = blockIdx.y * 64, n0 = blockIdx.x * 64;
  int tr = threadIdx.x >> 4, tc = threadIdx.x & 15;
#pragma unroll
  for (int i = 0; i < 4; i++) {
    int row = tr + i * 16;
    float4 v = *(const float4*)(W + (size_t)(k0 + row) * EMBED + n0 + tc * 4);
    tile[row][tc * 4 + 0] = (bf16)v.x;
    tile[row][tc * 4 + 1] = (bf16)v.y;
    tile[row][tc * 4 + 2] = (bf16)v.z;
    tile[row][tc * 4 + 3] = (bf16)v.w;
  }
  __syncthreads();
#pragma unroll
  for (int i = 0; i < 4; i++) {
    int nl = tr + i * 16;
    bf16 o[4] __attribute__((aligned(8)));
#pragma unroll
    for (int j = 0; j < 4; j++) o[j] = tile[tc * 4 + j][nl];
    *(ushort4*)(Wt + (size_t)(n0 + nl) * EMBED + k0 + tc * 4) = *(const ushort4*)o;
  }
}

__global__ __launch_bounds__(256) void transpose_cast(const float* __restrict__ W,
                                                      bf16* __restrict__ Wt) {
  transpose_body(W, Wt);
}

// merged: z selects Wq/Wk/Wv -> Wt3 + z*E*E
__global__ __launch_bounds__(256) void transpose_cast3(const float* __restrict__ Wq,
                                                       const float* __restrict__ Wk,
                                                       const float* __restrict__ Wv,
                                                       bf16* __restrict__ Wt3) {
  int z = blockIdx.z;
  const float* W = (z == 0) ? Wq : (z == 1) ? Wk : Wv;
  transpose_body(W, Wt3 + (size_t)z * EMBED * EMBED);
}

// ---------------- pipelined GEMM core (R13-proven) ----------------------------
// BM=128, BN=256, BK=64; 512 threads = 8 waves (2M x 4N), 64x64 per wave.
// Triple-buffered LDS (144 KB), prefetch depth 2, ONE barrier per K-tile,
// counted vmcnt(6) (T3+T4), XOR swizzle (T2, conflicts=0).
// mode 1: rotary bf16 out (Q,K); 2: V-transposed bf16 out; 3: fp32 out.
__device__ __forceinline__ void gemm_body(const bf16* __restrict__ A,
                                          const bf16* __restrict__ Bt,
                                          void* __restrict__ Cout,
                                          int M, int N, int K, int mode,
                                          int bx, int by) {
  constexpr int BM = 128, BN = 256, BK = 64;
  __shared__ __align__(16) bf16 As[3][BM * BK];  // 3 x 16 KB
  __shared__ __align__(16) bf16 Bs[3][BN * BK];  // 3 x 32 KB
  int t = threadIdx.x;
  int lane = t & 63, w = t >> 6;
  int c16 = lane & 15, g4 = lane >> 4;
  int wm = w >> 2, wn = w & 3;
  int m0 = by * BM, n0 = bx * BN;
  int nt = K / BK;

  f32x4 acc[4][4] = {};

  auto stage = [&](int kt, int slot) {
    const bf16* Asrc = A + (size_t)m0 * K + kt * BK;
    const bf16* Bsrc = Bt + (size_t)n0 * K + kt * BK;
    bf16* Ad = As[slot];
    bf16* Bd = Bs[slot];
#pragma unroll
    for (int i = 0; i < 2; i++) {  // A: 1024 chunks / 512 threads
      int c = i * 512 + t;
      int row = c >> 3, col8 = c & 7;
      async_copy16(Asrc + (size_t)row * K + ((col8 ^ (row & 7)) * 8), Ad + c * 8);
    }
#pragma unroll
    for (int i = 0; i < 4; i++) {  // B: 2048 chunks / 512 threads
      int c = i * 512 + t;
      int row = c >> 3, col8 = c & 7;
      async_copy16(Bsrc + (size_t)row * K + ((col8 ^ (row & 7)) * 8), Bd + c * 8);
    }
  };

  // prologue: tiles 0 and 1 in flight; wait tile 0 (6 of 12 outstanding left)
  stage(0, 0);
  stage(1, 1);
  asm volatile("s_waitcnt vmcnt(6)" ::: "memory");
  __builtin_amdgcn_s_barrier();

  for (int kt = 0; kt < nt; kt++) {
    int slot = kt - (kt / 3) * 3;
    const bf16* Ab = As[slot];
    const bf16* Bb = Bs[slot];

    bf16x8 af[2][4], bfr[2][4];
#pragma unroll
    for (int kk = 0; kk < 2; kk++) {
#pragma unroll
      for (int fm = 0; fm < 4; fm++) {
        int row = wm * 64 + fm * 16 + c16;
        af[kk][fm] = *(const bf16x8*)(Ab + row * BK + (((kk * 4 + g4) ^ (row & 7)) * 8));
      }
#pragma unroll
      for (int fn = 0; fn < 4; fn++) {
        int row = wn * 64 + fn * 16 + c16;
        bfr[kk][fn] = *(const bf16x8*)(Bb + row * BK + (((kk * 4 + g4) ^ (row & 7)) * 8));
      }
    }
    if (kt + 2 < nt) {
      int s2 = (kt + 2) - ((kt + 2) / 3) * 3;
      stage(kt + 2, s2);
    }
    __builtin_amdgcn_s_setprio(1);
#pragma unroll
    for (int kk = 0; kk < 2; kk++)
#pragma unroll
      for (int fm = 0; fm < 4; fm++)
#pragma unroll
        for (int fn = 0; fn < 4; fn++)
          acc[fm][fn] = __builtin_amdgcn_mfma_f32_16x16x32_bf16(af[kk][fm], bfr[kk][fn],
                                                                acc[fm][fn], 0, 0, 0);
    __builtin_amdgcn_s_setprio(0);
    if (kt < nt - 2) {
      asm volatile("s_waitcnt vmcnt(6)" ::: "memory");
      __builtin_amdgcn_s_barrier();
    } else if (kt == nt - 2) {
      asm volatile("s_waitcnt vmcnt(0)" ::: "memory");
      __builtin_amdgcn_s_barrier();
    }
  }

  // epilogue (mode is block-uniform)
#pragma unroll
  for (int fm = 0; fm < 4; fm++) {
#pragma unroll
    for (int fn = 0; fn < 4; fn++) {
      int col = n0 + wn * 64 + fn * 16 + c16;
#pragma unroll
      for (int r = 0; r < 4; r++) {
        int row = m0 + wm * 64 + fm * 16 + g4 * 4 + r;
        float v = acc[fm][fn][r];
        if (mode == 1) {
          int d = col & (HDIM - 1);
          if (d < ROT) {  // wave-uniform: true iff wn==0
            float pv = __shfl_xor(v, 1);
            int jj = d >> 1;
            float invf = __expf(-0.28782313662425575f * (float)jj);
            float ang = (float)row * invf;
            float sa, ca;
            sincosf(ang, &sa, &ca);
            v = v * ca + pv * sa;  // reference has NO negation in rotate_every_two
          }
        }
        if (mode == 3) {
          ((float*)Cout)[(size_t)row * N + col] = v;
        } else if (mode == 2) {
          ((bf16*)Cout)[(size_t)col * M + row] = (bf16)v;
        } else {
          ((bf16*)Cout)[(size_t)row * N + col] = (bf16)v;
        }
      }
    }
  }
}

template <int MODE>
__global__ __launch_bounds__(512, 1) void gemm_pipe(const bf16* __restrict__ A,
                                                    const bf16* __restrict__ Bt,
                                                    void* __restrict__ Cout,
                                                    int M, int N, int K) {
  gemm_body(A, Bt, Cout, M, N, K, MODE, blockIdx.x, blockIdx.y);
}

// merged QKV GEMM: grid (16,16,3); z -> {weight, output, epilogue mode}.
// 768 blocks: CUs roll from Q tiles into K/V tiles (no per-kernel tail drain).
__global__ __launch_bounds__(512, 1) void gemm_qkv(const bf16* __restrict__ A,
                                                   const bf16* __restrict__ Wt3,
                                                   bf16* __restrict__ Qb,
                                                   bf16* __restrict__ Kb,
                                                   bf16* __restrict__ Vtb) {
  int z = blockIdx.z;
  const bf16* Bt = Wt3 + (size_t)z * EMBED * EMBED;
  void* out = (z == 0) ? (void*)Qb : (z == 1) ? (void*)Kb : (void*)Vtb;
  int mode = (z == 2) ? 2 : 1;
  gemm_body(A, Bt, out, SLEN, EMBED, EMBED, mode, blockIdx.x, blockIdx.y);
}

// ---------------- causal flash attention (R16-proven, unchanged) --------------
// 512 blocks, 2/CU; balanced pairing: pair (b, b+256) sums to 33 iters; shares
// h = b&15 (same K/V L2 lines; 2 heads/XCD). Ping-pong single-buffered K/V:
// QK(t) | barrier A | stage K(t+1) | softmax | PV(t) | barrier B | stage V(t+1).
// XOR-swizzle, defer-max (T13), per-lane lrow (R11).
__global__ __launch_bounds__(256, 2) void attn_kernel(const bf16* __restrict__ Q,
                                                      const bf16* __restrict__ Kmat,
                                                      const bf16* __restrict__ Vt,
                                                      bf16* __restrict__ O) {
  __shared__ __align__(16) bf16 Ks[64 * 256];   // [kv_row][d], swizzled (32 KB)
  __shared__ __align__(16) bf16 Vs[64 * 256];   // [d][kv_row], swizzled (32 KB)
  __shared__ __align__(16) bf16 Pl[4][16 * 64]; // per-wave P, swizzled (8 KB)
  int t = threadIdx.x, lane = t & 63, w = t >> 6;
  int c16 = lane & 15, g4 = lane >> 4;
  int b = blockIdx.x;
  int bb = b & 255;
  int h = bb & 15;
  int k = bb >> 4;                       // 0..15
  int qt = (b >> 8) ? k : (31 - k);      // heavy half first; pair sums to 33
  int q0w = qt * 64 + w * 16;

  auto stageK = [&](int kt) {
#pragma unroll
    for (int j = 0; j < 8; j++) {
      int c = j * 256 + t;
      int row = c >> 5, col8 = c & 31;
      async_copy16(Kmat + (size_t)(kt * 64 + row) * EMBED + h * HDIM +
                       ((col8 ^ (row & 7)) * 8),
                   Ks + (size_t)c * 8);
    }
  };
  auto stageV = [&](int kt) {
#pragma unroll
    for (int j = 0; j < 8; j++) {
      int c = j * 256 + t;
      int row = c >> 3, col8 = c & 7;
      async_copy16(Vt + (size_t)(h * HDIM + row) * SLEN + kt * 64 +
                       ((col8 ^ (row & 7)) * 8),
                   Vs + (size_t)c * 8);
    }
  };

  bf16x8 qf[8];
  {
    const bf16* qp = Q + (size_t)(q0w + c16) * EMBED + h * HDIM + g4 * 8;
#pragma unroll
    for (int kk = 0; kk < 8; kk++) qf[kk] = *(const bf16x8*)(qp + kk * 32);
  }
  f32x4 acco[16] = {};
  float mrow[4], lrow[4];  // mrow row-uniform; lrow PER-LANE partial
#pragma unroll
  for (int r = 0; r < 4; r++) { mrow[r] = -1e30f; lrow[r] = 0.f; }

  stageK(0);
  stageV(0);
  __syncthreads();  // drain: K(0), V(0) resident

  for (int kt = 0; kt <= qt; kt++) {
    // ---- QK(t) from Ks ----
    f32x4 accs[4] = {};
    __builtin_amdgcn_s_setprio(1);
#pragma unroll
    for (int kk = 0; kk < 8; kk++) {
#pragma unroll
      for (int fn = 0; fn < 4; fn++) {
        int r = fn * 16 + c16;
        bf16x8 kf = *(const bf16x8*)(Ks + r * 256 + ((kk * 4 + g4) ^ (c16 & 7)) * 8);
        accs[fn] = __builtin_amdgcn_mfma_f32_16x16x32_bf16(qf[kk], kf, accs[fn], 0, 0, 0);
      }
    }
    __builtin_amdgcn_s_setprio(0);
    __syncthreads();  // barrier A: frees Ks; drains V(t) staging
    if (kt < qt) stageK(kt + 1);  // in flight under softmax + PV

    // ---- softmax ----
    float pm[4][4];
    bool diag = (kt == qt);
#pragma unroll
    for (int fn = 0; fn < 4; fn++)
#pragma unroll
      for (int r = 0; r < 4; r++) {
        float s = accs[fn][r] * 0.0625f;  // 1/sqrt(256); mask-before-scale == -1e30
        if (diag) {
          int kg = fn * 16 + c16;
          int qg = w * 16 + g4 * 4 + r;
          if (kg > qg) s = -1e30f;
        }
        pm[fn][r] = s;
      }
    float lmax[4];
#pragma unroll
    for (int r = 0; r < 4; r++)
      lmax[r] = fmaxf(fmaxf(pm[0][r], pm[1][r]), fmaxf(pm[2][r], pm[3][r]));
    bool need = false;
#pragma unroll
    for (int r = 0; r < 4; r++) need = need || (lmax[r] > mrow[r] + 8.0f);
    if (__any(need)) {  // rare: full max-reduce + rescale only here
#pragma unroll
      for (int r = 0; r < 4; r++) {
        float mx = lmax[r];
#pragma unroll
        for (int off = 1; off < 16; off <<= 1) mx = fmaxf(mx, __shfl_xor(mx, off));
        float mn = fmaxf(mrow[r], mx);
        float sc = __expf(mrow[r] - mn);
        mrow[r] = mn;
        lrow[r] *= sc;
#pragma unroll
        for (int fd = 0; fd < 16; fd++) acco[fd][r] *= sc;
      }
    }
#pragma unroll
    for (int fn = 0; fn < 4; fn++)
#pragma unroll
      for (int r = 0; r < 4; r++) {
        float p = __expf(pm[fn][r] - mrow[r]);
        pm[fn][r] = p;
        lrow[r] += p;
      }
#pragma unroll
    for (int fn = 0; fn < 4; fn++)
#pragma unroll
      for (int r = 0; r < 4; r++) {
        int q = g4 * 4 + r;
        int chunk = (fn * 2 + (c16 >> 3)) ^ (q & 7);
        Pl[w][q * 64 + chunk * 8 + (c16 & 7)] = (bf16)pm[fn][r];
      }
    // ---- PV(t) from Vs ----
    __builtin_amdgcn_s_setprio(1);
#pragma unroll
    for (int kk2 = 0; kk2 < 2; kk2++) {
      bf16x8 pf = *(const bf16x8*)(&Pl[w][c16 * 64 + ((kk2 * 4 + g4) ^ (c16 & 7)) * 8]);
#pragma unroll
      for (int fd = 0; fd < 16; fd++) {
        int rv = fd * 16 + c16;
        bf16x8 vf = *(const bf16x8*)(Vs + rv * 64 + ((kk2 * 4 + g4) ^ (c16 & 7)) * 8);
        acco[fd] = __builtin_amdgcn_mfma_f32_16x16x32_bf16(pf, vf, acco[fd], 0, 0, 0);
      }
    }
    __builtin_amdgcn_s_setprio(0);
    __syncthreads();  // barrier B: frees Vs; drains K(t+1) staging
    if (kt < qt) stageV(kt + 1);  // in flight under next QK
  }
  // epilogue: one row-wide sum-reduce of the per-lane lrow partials
  float inv[4];
#pragma unroll
  for (int r = 0; r < 4; r++) {
    float s = lrow[r];
#pragma unroll
    for (int off = 1; off < 16; off <<= 1) s += __shfl_xor(s, off);
    inv[r] = 1.0f / s;
  }
#pragma unroll
  for (int fd = 0; fd < 16; fd++)
#pragma unroll
    for (int r = 0; r < 4; r++) {
      int qg = q0w + g4 * 4 + r;
      int col = h * HDIM + fd * 16 + c16;
      O[(size_t)qg * EMBED + col] = (bf16)(acco[fd][r] * inv[r]);
    }
}

extern "C" void kernel_launch(void* const* d_in, const int* in_sizes, int n_in,
                              void* d_out, int out_size, void* d_ws, size_t ws_size,
                              hipStream_t stream) {
  const float* hidden = (const float*)d_in[0];
  const float* Wq = (const float*)d_in[1];
  const float* Wk = (const float*)d_in[2];
  const float* Wv = (const float*)d_in[3];
  const float* Wo = (const float*)d_in[4];
  float* out = (float*)d_out;

  char* ws = (char*)d_ws;
  const size_t SZ_H = (size_t)SLEN * EMBED * 2;   // 16 MiB
  const size_t SZ_W = (size_t)EMBED * EMBED * 2;  // 32 MiB

  dim3 tgrid(EMBED / 64, EMBED / 64);
  dim3 ggrid(EMBED / 256, SLEN / 128);  // 16 x 16 = 256 blocks

  if (ws_size >= 5 * SZ_H + 3 * SZ_W) {
    // merged path (176 MiB): fewer launches; QKV GEMM = one 768-block kernel.
    bf16* h_bf = (bf16*)ws;
    bf16* Wt3  = (bf16*)(ws + SZ_H);
    bf16* Qb   = (bf16*)(ws + SZ_H + 3 * SZ_W);
    bf16* Kb   = (bf16*)(ws + 2 * SZ_H + 3 * SZ_W);
    bf16* Vtb  = (bf16*)(ws + 3 * SZ_H + 3 * SZ_W);
    bf16* Ob   = (bf16*)(ws + 4 * SZ_H + 3 * SZ_W);

    cast_kernel<<<(SLEN * EMBED / 4 + 255) / 256, 256, 0, stream>>>(
        hidden, h_bf, SLEN * EMBED / 4);
    transpose_cast3<<<dim3(EMBED / 64, EMBED / 64, 3), 256, 0, stream>>>(Wq, Wk,
                                                                         Wv, Wt3);
    gemm_qkv<<<dim3(EMBED / 256, SLEN / 128, 3), 512, 0, stream>>>(h_bf, Wt3, Qb,
                                                                   Kb, Vtb);
    attn_kernel<<<dim3(512), 256, 0, stream>>>(Qb, Kb, Vtb, Ob);
    transpose_cast<<<tgrid, 256, 0, stream>>>(Wo, Wt3);
    gemm_pipe<3><<<ggrid, 512, 0, stream>>>(Ob, Wt3, out, SLEN, EMBED, EMBED);
    return;
  }

  // fallback (112 MiB, exactly the R16-proven sequence)
  if (ws_size < 5 * SZ_H + SZ_W) return;
  bf16* h_bf = (bf16*)ws;
  bf16* Wt   = (bf16*)(ws + SZ_H);
  bf16* Qb   = (bf16*)(ws + SZ_H + SZ_W);
  bf16* Kb   = (bf16*)(ws + 2 * SZ_H + SZ_W);
  bf16* Vtb  = (bf16*)(ws + 3 * SZ_H + SZ_W);
  bf16* Ob   = (bf16*)(ws + 4 * SZ_H + SZ_W);

  cast_kernel<<<(SLEN * EMBED / 4 + 255) / 256, 256, 0, stream>>>(hidden, h_bf,
                                                                  SLEN * EMBED / 4);
  transpose_cast<<<tgrid, 256, 0, stream>>>(Wq, Wt);
  gemm_pipe<1><<<ggrid, 512, 0, stream>>>(h_bf, Wt, Qb, SLEN, EMBED, EMBED);
  transpose_cast<<<tgrid, 256, 0, stream>>>(Wk, Wt);
  gemm_pipe<1><<<ggrid, 512, 0, stream>>>(h_bf, Wt, Kb, SLEN, EMBED, EMBED);
  transpose_cast<<<tgrid, 256, 0, stream>>>(Wv, Wt);
  gemm_pipe<2><<<ggrid, 512, 0, stream>>>(h_bf, Wt, Vtb, SLEN, EMBED, EMBED);
  attn_kernel<<<dim3(512), 256, 0, stream>>>(Qb, Kb, Vtb, Ob);
  transpose_cast<<<tgrid, 256, 0, stream>>>(Wo, Wt);
  gemm_pipe<3><<<ggrid, 512, 0, stream>>>(Ob, Wt, out, SLEN, EMBED, EMBED);
}